// Round 6
// baseline (1359.840 us; speedup 1.0000x reference)
//
#include <hip/hip_runtime.h>
#include <math.h>

#define NN 50000
#define EE 800000
#define RR 8
#define SLOPE 0.2f
#define SEGS (NN * RR)            /* 400000 per-(node,relation) segments */
#define NBLK ((SEGS + 255) / 256) /* 1563 scan blocks */

__device__ __forceinline__ float leaky(float v) { return v >= 0.f ? v : SLOPE * v; }

// ============================ CSR build ============================
__global__ void k_count2(const int* __restrict__ dst, const int* __restrict__ et,
                         int* __restrict__ cnt2) {
    int e = blockIdx.x * 256 + threadIdx.x;
    if (e < EE) atomicAdd(&cnt2[dst[e] * RR + et[e]], 1);
}

__global__ void k_scanA(const int* __restrict__ cnt2, int* __restrict__ rp,
                        int* __restrict__ bsum) {
    __shared__ int sh[256];
    int t = threadIdx.x;
    int i = blockIdx.x * 256 + t;
    int v = (i < SEGS) ? cnt2[i] : 0;
    sh[t] = v;
    __syncthreads();
    for (int off = 1; off < 256; off <<= 1) {
        int u = (t >= off) ? sh[t - off] : 0;
        __syncthreads();
        sh[t] += u;
        __syncthreads();
    }
    if (i < SEGS) rp[i] = sh[t] - v;
    if (t == 255) bsum[blockIdx.x] = sh[255];
}

__global__ void k_scanB(int* __restrict__ bsum) {
    __shared__ int sh[256];
    int t = threadIdx.x;
    int loc[8];
    int s = 0;
#pragma unroll
    for (int i = 0; i < 8; i++) {
        int idx = t * 8 + i;
        int v = (idx < NBLK) ? bsum[idx] : 0;
        loc[i] = v;
        s += v;
    }
    sh[t] = s;
    __syncthreads();
    for (int off = 1; off < 256; off <<= 1) {
        int u = (t >= off) ? sh[t - off] : 0;
        __syncthreads();
        sh[t] += u;
        __syncthreads();
    }
    int run = sh[t] - s;
#pragma unroll
    for (int i = 0; i < 8; i++) {
        int idx = t * 8 + i;
        if (idx < NBLK) {
            int v = loc[i];
            bsum[idx] = run;
            run += v;
        }
    }
}

__global__ void k_scanC(int* __restrict__ rp, const int* __restrict__ bsum,
                        int* __restrict__ wo) {
    int i = blockIdx.x * 256 + threadIdx.x;
    if (i < SEGS) {
        int v = rp[i] + bsum[blockIdx.x];
        rp[i] = v;
        wo[i] = v;
    }
    if (i == 0) rp[SEGS] = EE;
}

// fill srcs (plain src ids, dst-major/relation-minor sorted) + per-edge scale 1/cnt
__global__ void k_fill(const int* __restrict__ src, const int* __restrict__ dst,
                       const int* __restrict__ et, const int* __restrict__ cnt2,
                       int* __restrict__ wo, int* __restrict__ srcs,
                       float* __restrict__ esc) {
    int e = blockIdx.x * 256 + threadIdx.x;
    if (e >= EE) return;
    int seg = dst[e] * RR + et[e];
    int pos = atomicAdd(&wo[seg], 1);
    srcs[pos] = src[e];
    esc[pos] = 1.f / (float)cnt2[seg];  // cnt2[seg] >= 1 (this edge exists)
}

// ============ compose W_r = sum_b comp[r,b] * basis[b] (both layers) ============
__global__ void k_weights(const float* __restrict__ basis1, const float* __restrict__ comp1,
                          const float* __restrict__ basis2, const float* __restrict__ comp2,
                          float* __restrict__ W1, float* __restrict__ W2) {
    int idx = blockIdx.x * 256 + threadIdx.x;
    if (idx < RR * 64 * 64) {
        int r = idx >> 12, io = idx & 4095;
        float acc = 0.f;
#pragma unroll
        for (int b = 0; b < 4; b++) acc += comp1[r * 4 + b] * basis1[b * 4096 + io];
        W1[idx] = acc;
    } else if (idx < 2 * RR * 64 * 64) {
        int j = idx - RR * 64 * 64;
        int r = j >> 12, io = j & 4095;
        float acc = 0.f;
#pragma unroll
        for (int b = 0; b < 4; b++) acc += comp2[r * 4 + b] * basis2[b * 4096 + io];
        W2[j] = acc;
    }
}

// ============ transform 1: y[rr][n][64] = x[n] @ W_{r0+rr}; 8 nodes/wave ============
__global__ __launch_bounds__(256) void k_trans1(const float* __restrict__ X,
                                                const float* __restrict__ W,
                                                float* __restrict__ y,
                                                int r0, int nrel) {
    int wid = threadIdx.x >> 6, lane = threadIdx.x & 63;
    int n0 = (blockIdx.x * 4 + wid) * 8;
    if (n0 >= NN) return;  // NN % 8 == 0
    float m[8];
#pragma unroll
    for (int j = 0; j < 8; j++) m[j] = X[(size_t)(n0 + j) * 64 + lane];
    for (int rr = 0; rr < nrel; rr++) {
        const float* Wr = W + (size_t)(r0 + rr) * 4096;
        float acc[8];
#pragma unroll
        for (int j = 0; j < 8; j++) acc[j] = 0.f;
#pragma unroll 16
        for (int i = 0; i < 64; i++) {
            float wv = Wr[i * 64 + lane];
#pragma unroll
            for (int j = 0; j < 8; j++) acc[j] += __shfl(m[j], i) * wv;
        }
#pragma unroll
        for (int j = 0; j < 8; j++)
            y[((size_t)rr * NN + (n0 + j)) * 64 + lane] = acc[j];
    }
}

// ============ aggregate 1: per-node wave, nested per-relation loop, esc weights ============
__global__ __launch_bounds__(256) void k_agg1(const int* __restrict__ rp,
                                              const int* __restrict__ srcs,
                                              const float* __restrict__ esc,
                                              const float* __restrict__ y,
                                              const float* __restrict__ X,
                                              const float* __restrict__ root,
                                              const float* __restrict__ bias,
                                              float* __restrict__ x1,
                                              int r0, int nrel) {
    int wid = threadIdx.x >> 6, lane = threadIdx.x & 63;
    int n = blockIdx.x * 4 + wid;
    if (n >= NN) return;
    float acc = (r0 == 0) ? 0.f : x1[(size_t)n * 64 + lane];
    for (int rr = 0; rr < nrel; rr++) {
        int beg = rp[n * RR + r0 + rr], end = rp[n * RR + r0 + rr + 1];
        const float* yr = y + (size_t)rr * NN * 64;
        int k = beg;
        for (; k + 2 <= end; k += 2) {
            int sa = srcs[k], sb = srcs[k + 1];
            float ea = esc[k], eb = esc[k + 1];
            float va = yr[(size_t)sa * 64 + lane];
            float vb = yr[(size_t)sb * 64 + lane];
            acc += va * ea + vb * eb;
        }
        if (k < end) acc += yr[(size_t)srcs[k] * 64 + lane] * esc[k];
    }
    if (r0 + nrel == RR) {
        float xv = X[(size_t)n * 64 + lane];
        float rsum = bias[lane];
#pragma unroll 16
        for (int i = 0; i < 64; i++) rsum += __shfl(xv, i) * root[i * 64 + lane];
        x1[(size_t)n * 64 + lane] = fmaxf(acc + rsum, 0.f);
    } else {
        x1[(size_t)n * 64 + lane] = acc;
    }
}

// ============ transform 2: y[rr][n][32] = x2[n](128) @ W2_{r0+rr}; 8 nodes/wave ============
// split-half matvec (proven in R4's k_rgcn2f): ih=lane>>5 owns input rows ih*64..+63.
__global__ __launch_bounds__(256) void k_trans2(const float* __restrict__ X,
                                                const float* __restrict__ W,
                                                float* __restrict__ y,
                                                int r0, int nrel) {
    int wid = threadIdx.x >> 6, lane = threadIdx.x & 63;
    int n0 = (blockIdx.x * 4 + wid) * 8;
    if (n0 >= NN) return;
    const int ih = lane >> 5, ol = lane & 31;
    const int gbase = ih * 64 + ol;
    const int sl = ih * 32;
    const int wb = ih * 2048 + ol;
    float mA[8], mB[8];
#pragma unroll
    for (int j = 0; j < 8; j++) {
        mA[j] = X[(size_t)(n0 + j) * 128 + gbase];
        mB[j] = X[(size_t)(n0 + j) * 128 + gbase + 32];
    }
    for (int rr = 0; rr < nrel; rr++) {
        const float* Wr = W + (size_t)(r0 + rr) * 4096;
        float acc[8];
#pragma unroll
        for (int j = 0; j < 8; j++) acc[j] = 0.f;
#pragma unroll 8
        for (int i = 0; i < 64; i++) {
            float wv = Wr[wb + i * 32];
#pragma unroll
            for (int j = 0; j < 8; j++) {
                float v = (i < 32) ? __shfl(mA[j], sl + (i & 31)) : __shfl(mB[j], sl + (i & 31));
                acc[j] += v * wv;
            }
        }
#pragma unroll
        for (int j = 0; j < 8; j++) {
            acc[j] += __shfl_xor(acc[j], 32);
            if (ih == 0) y[((size_t)rr * NN + (n0 + j)) * 32 + ol] = acc[j];
        }
    }
}

// ============ aggregate 2: per-node wave; both halves duplicate-compute 32 channels ============
__global__ __launch_bounds__(256) void k_agg2(const int* __restrict__ rp,
                                              const int* __restrict__ srcs,
                                              const float* __restrict__ esc,
                                              const float* __restrict__ y,
                                              const float* __restrict__ X2,
                                              const float* __restrict__ root,
                                              const float* __restrict__ bias,
                                              float* __restrict__ x3,
                                              int r0, int nrel) {
    int wid = threadIdx.x >> 6, lane = threadIdx.x & 63;
    int n = blockIdx.x * 4 + wid;
    if (n >= NN) return;
    const int ol = lane & 31;
    float acc = (r0 == 0) ? 0.f : x3[(size_t)n * 32 + ol];
    for (int rr = 0; rr < nrel; rr++) {
        int beg = rp[n * RR + r0 + rr], end = rp[n * RR + r0 + rr + 1];
        const float* yr = y + (size_t)rr * NN * 32;
        int k = beg;
        for (; k + 2 <= end; k += 2) {
            int sa = srcs[k], sb = srcs[k + 1];
            float ea = esc[k], eb = esc[k + 1];
            float va = yr[(size_t)sa * 32 + ol];
            float vb = yr[(size_t)sb * 32 + ol];
            acc += va * ea + vb * eb;
        }
        if (k < end) acc += yr[(size_t)srcs[k] * 32 + ol] * esc[k];
    }
    if (r0 + nrel == RR) {
        float xvA = X2[(size_t)n * 128 + lane];
        float xvB = X2[(size_t)n * 128 + 64 + lane];
        float rsum = bias[ol];
#pragma unroll 16
        for (int i = 0; i < 64; i++) rsum += __shfl(xvA, i) * root[i * 32 + ol];
#pragma unroll 16
        for (int i = 0; i < 64; i++) rsum += __shfl(xvB, i) * root[(64 + i) * 32 + ol];
        if (lane < 32) x3[(size_t)n * 32 + ol] = fmaxf(acc + rsum, 0.f);
    } else {
        if (lane < 32) x3[(size_t)n * 32 + ol] = acc;
    }
}

// ============ dense projection Y[N,OUT] = X[N,IN] @ W[IN,OUT] ============
template <int IN, int OUT>
__global__ __launch_bounds__(256) void k_dense(const float* __restrict__ X,
                                               const float* __restrict__ W,
                                               float* __restrict__ Y) {
    int wid = threadIdx.x >> 6, lane = threadIdx.x & 63;
    int g = blockIdx.x * 4 + wid;
    int n0 = g * 8;
    if (n0 >= NN) return;
    constexpr int NO = OUT / 64;
    float m[8];
#pragma unroll
    for (int j = 0; j < 8; j++) {
        int n = n0 + j;
        m[j] = (n < NN && (IN == 64 || lane < IN)) ? X[(size_t)n * IN + (lane % IN)] : 0.f;
    }
    float acc[8][NO];
#pragma unroll
    for (int j = 0; j < 8; j++)
#pragma unroll
        for (int q = 0; q < NO; q++) acc[j][q] = 0.f;
#pragma unroll 16
    for (int i = 0; i < IN; i++) {
        float wv[NO];
#pragma unroll
        for (int q = 0; q < NO; q++) wv[q] = W[i * OUT + q * 64 + lane];
#pragma unroll
        for (int j = 0; j < 8; j++) {
            float v = __shfl(m[j], i);
#pragma unroll
            for (int q = 0; q < NO; q++) acc[j][q] += v * wv[q];
        }
    }
#pragma unroll
    for (int j = 0; j < 8; j++) {
        int n = n0 + j;
        if (n < NN) {
#pragma unroll
            for (int q = 0; q < NO; q++) Y[(size_t)n * OUT + q * 64 + lane] = acc[j][q];
        }
    }
}

// ===================== attention logits =====================
__global__ void k_gat_al(const float* __restrict__ h, const float* __restrict__ a_src,
                         const float* __restrict__ a_dst, float* __restrict__ als,
                         float* __restrict__ ald, int C) {
    int i = blockIdx.x * 256 + threadIdx.x;  // i = n*4 + hh
    if (i >= NN * 4) return;
    int hh = i & 3;
    const float* hp = h + (size_t)i * C;
    float a = 0.f, b = 0.f;
    for (int c = 0; c < C; c++) {
        float v = hp[c];
        a += v * a_src[hh * C + c];
        b += v * a_dst[hh * C + c];
    }
    als[i] = a;
    ald[i] = b;
}

// ============ fused per-dst GAT, one pass (logits O(1): no max needed), unroll-4 ============
// byte-identical to the R4 kernel that passed.
template <int HC, int C, bool MEANOUT>
__global__ __launch_bounds__(256) void k_gat(const int* __restrict__ rp,
                                             const int* __restrict__ srcs,
                                             const float* __restrict__ als,
                                             const float* __restrict__ ald,
                                             const float* __restrict__ h,
                                             const float* __restrict__ bias,
                                             float* __restrict__ out) {
    int wid = threadIdx.x >> 6, lane = threadIdx.x & 63;
    int n = blockIdx.x * 4 + wid;
    if (n >= NN) return;
    constexpr bool TWO = (HC == 128);
    const int hh0 = lane / C;
    const int hh1 = TWO ? (2 + lane / C) : 0;
    float aldd0 = ald[n * 4 + hh0];
    float z0 = __expf(leaky(als[n * 4 + hh0] + aldd0));
    float acc0 = z0 * h[(size_t)n * HC + lane];
    float aldd1 = 0.f, z1 = 0.f, acc1 = 0.f;
    if (TWO) {
        aldd1 = ald[n * 4 + hh1];
        z1 = __expf(leaky(als[n * 4 + hh1] + aldd1));
        acc1 = z1 * h[(size_t)n * HC + 64 + lane];
    }
    int beg = rp[n * RR], end = rp[n * RR + RR];
    int k = beg;
    for (; k + 4 <= end; k += 4) {
        int s[4];
#pragma unroll
        for (int u = 0; u < 4; u++) s[u] = srcs[k + u];
        float q0[4], q1[4], hv0[4], hv1[4];
#pragma unroll
        for (int u = 0; u < 4; u++) q0[u] = als[s[u] * 4 + hh0];
        if (TWO) {
#pragma unroll
            for (int u = 0; u < 4; u++) q1[u] = als[s[u] * 4 + hh1];
        }
#pragma unroll
        for (int u = 0; u < 4; u++) hv0[u] = h[(size_t)s[u] * HC + lane];
        if (TWO) {
#pragma unroll
            for (int u = 0; u < 4; u++) hv1[u] = h[(size_t)s[u] * HC + 64 + lane];
        }
#pragma unroll
        for (int u = 0; u < 4; u++) {
            float p0 = __expf(leaky(q0[u] + aldd0));
            z0 += p0;
            acc0 += p0 * hv0[u];
            if (TWO) {
                float p1 = __expf(leaky(q1[u] + aldd1));
                z1 += p1;
                acc1 += p1 * hv1[u];
            }
        }
    }
    for (; k < end; k++) {
        int s = srcs[k];
        float p0 = __expf(leaky(als[s * 4 + hh0] + aldd0));
        z0 += p0;
        acc0 += p0 * h[(size_t)s * HC + lane];
        if (TWO) {
            float p1 = __expf(leaky(als[s * 4 + hh1] + aldd1));
            z1 += p1;
            acc1 += p1 * h[(size_t)s * HC + 64 + lane];
        }
    }
    if (!MEANOUT) {
        out[(size_t)n * HC + lane] = acc0 / z0 + bias[lane];
        if (TWO) out[(size_t)n * HC + 64 + lane] = acc1 / z1 + bias[64 + lane];
    } else {
        float v = acc0 / z0;
        v += __shfl_xor(v, 16);
        v += __shfl_xor(v, 32);
        if (lane < 16) {
            float o2 = 0.25f * v + bias[lane];
            o2 = fmaxf(o2, 0.f);
            out[n * 16 + lane] = tanhf(o2);
        }
    }
}

extern "C" void kernel_launch(void* const* d_in, const int* in_sizes, int n_in,
                              void* d_out, int out_size, void* d_ws, size_t ws_size,
                              hipStream_t stream) {
    const float* x      = (const float*)d_in[0];
    const int*   ei     = (const int*)d_in[1];
    const int*   et     = (const int*)d_in[2];
    const float* basis1 = (const float*)d_in[3];
    const float* comp1  = (const float*)d_in[4];
    const float* root1  = (const float*)d_in[5];
    const float* brg1   = (const float*)d_in[6];
    const float* wg1    = (const float*)d_in[7];
    const float* asrc1  = (const float*)d_in[8];
    const float* adst1  = (const float*)d_in[9];
    const float* bg1    = (const float*)d_in[10];
    const float* basis2 = (const float*)d_in[11];
    const float* comp2  = (const float*)d_in[12];
    const float* root2  = (const float*)d_in[13];
    const float* brg2   = (const float*)d_in[14];
    const float* wg2    = (const float*)d_in[15];
    const float* asrc2  = (const float*)d_in[16];
    const float* adst2  = (const float*)d_in[17];
    const float* bg2    = (const float*)d_in[18];
    const int* src = ei;
    const int* dst = ei + EE;
    float* out = (float*)d_out;

    // ---- int region ----
    int* wsi = (int*)d_ws;
    size_t ioff = 0;
    auto ialloc = [&](size_t n) { int* p = wsi + ioff; ioff += (n + 3) & ~(size_t)3; return p; };
    int* cnt2 = ialloc(SEGS);
    int* rp   = ialloc(SEGS + 1);
    int* wo   = ialloc(SEGS + 1);
    int* bsum = ialloc(2048);
    int* srcs = ialloc(EE);
    // ---- float region ----
    float* wsf = (float*)(wsi + ioff);
    size_t total_f = (ws_size - ioff * sizeof(int)) / sizeof(float);
    // choose relation-block config by available space
    auto max3 = [](size_t a, size_t b, size_t c) {
        size_t m = a > b ? a : b; return m > c ? m : c;
    };
    size_t fixed_f = (size_t)EE                  // esc
                   + (size_t)NN * 64             // x1 / x3
                   + (size_t)NN * 128            // x2 / h2
                   + 2 * (size_t)RR * 4096       // W1, W2
                   + 2 * (size_t)NN * 4 + 64;    // als, ald + align slack
    int nrel1 = 4, nrel2 = 8;
    size_t ybuf_f = max3((size_t)nrel1 * NN * 64, (size_t)nrel2 * NN * 32, (size_t)NN * 128);
    if (total_f < fixed_f + ybuf_f) {
        nrel1 = 2; nrel2 = 4;
        ybuf_f = max3((size_t)nrel1 * NN * 64, (size_t)nrel2 * NN * 32, (size_t)NN * 128);
        if (total_f < fixed_f + ybuf_f) return;  // loud fail: output stays zero
    }
    size_t foff = 0;
    auto falloc = [&](size_t n) { float* p = wsf + foff; foff += (n + 3) & ~(size_t)3; return p; };
    float* esc  = falloc(EE);
    float* ybuf = falloc(ybuf_f);
    float* x1   = falloc((size_t)NN * 64);   // also x3
    float* x2   = falloc((size_t)NN * 128);  // also h2
    float* W1   = falloc((size_t)RR * 4096);
    float* W2   = falloc((size_t)RR * 4096);
    float* als  = falloc((size_t)NN * 4);
    float* ald  = falloc((size_t)NN * 4);
    float* h1 = ybuf;  // alias: ybuf dead between last agg1 and first trans2
    float* x3 = x1;    // alias: x1 dead after k_dense(x1 -> h1)
    float* h2 = x2;    // alias: x2 dead after last trans2/agg2

    const int EB = (EE + 255) / 256;
    const int NB4 = (NN + 3) / 4;      // one node per wave (256 thr = 4 waves)
    const int NTB = (NN / 8 + 3) / 4;  // 8 nodes per wave

    // ---- CSR build (dst,relation)-sorted ----
    hipMemsetAsync(cnt2, 0, SEGS * sizeof(int), stream);
    k_count2<<<EB, 256, 0, stream>>>(dst, et, cnt2);
    k_scanA<<<NBLK, 256, 0, stream>>>(cnt2, rp, bsum);
    k_scanB<<<1, 256, 0, stream>>>(bsum);
    k_scanC<<<NBLK, 256, 0, stream>>>(rp, bsum, wo);
    k_fill<<<EB, 256, 0, stream>>>(src, dst, et, cnt2, wo, srcs, esc);
    k_weights<<<(2 * RR * 4096) / 256, 256, 0, stream>>>(basis1, comp1, basis2, comp2, W1, W2);

    // ---- layer 1: RGCN(64->64) + relu (transform -> gather) ----
    for (int r0 = 0; r0 < RR; r0 += nrel1) {
        k_trans1<<<NTB, 256, 0, stream>>>(x, W1, ybuf, r0, nrel1);
        k_agg1<<<NB4, 256, 0, stream>>>(rp, srcs, esc, ybuf, x, root1, brg1, x1, r0, nrel1);
    }

    // ---- layer 2: GAT(64 -> 4x32 concat) ----
    k_dense<64, 128><<<NTB, 256, 0, stream>>>(x1, wg1, h1);
    k_gat_al<<<(NN * 4 + 255) / 256, 256, 0, stream>>>(h1, asrc1, adst1, als, ald, 32);
    k_gat<128, 32, false><<<NB4, 256, 0, stream>>>(rp, srcs, als, ald, h1, bg1, x2);

    // ---- layer 3: RGCN(128->32) + relu (transform -> gather) ----
    for (int r0 = 0; r0 < RR; r0 += nrel2) {
        k_trans2<<<NTB, 256, 0, stream>>>(x2, W2, ybuf, r0, nrel2);
        k_agg2<<<NB4, 256, 0, stream>>>(rp, srcs, esc, ybuf, x2, root2, brg2, x3, r0, nrel2);
    }

    // ---- layer 4: GAT(32 -> 4x16, mean heads) + relu + tanh ----
    k_dense<32, 64><<<NTB, 256, 0, stream>>>(x3, wg2, h2);
    k_gat_al<<<(NN * 4 + 255) / 256, 256, 0, stream>>>(h2, asrc2, adst2, als, ald, 16);
    k_gat<64, 16, true><<<NB4, 256, 0, stream>>>(rp, srcs, als, ald, h2, bg2, out);
}

// Round 7
// 686.780 us; speedup vs baseline: 1.9800x; 1.9800x over previous
//
#include <hip/hip_runtime.h>
#include <math.h>

#define NN 50000
#define EE 800000
#define RR 8
#define SLOPE 0.2f
#define SEGS (NN * RR)            /* 400000 per-(node,relation) segments */
#define NBLK ((SEGS + 255) / 256) /* 1563 scan blocks */

__device__ __forceinline__ float leaky(float v) { return v >= 0.f ? v : SLOPE * v; }

// ============================ CSR build ============================
__global__ void k_count2(const int* __restrict__ dst, const int* __restrict__ et,
                         int* __restrict__ cnt2) {
    int e = blockIdx.x * 256 + threadIdx.x;
    if (e < EE) atomicAdd(&cnt2[dst[e] * RR + et[e]], 1);
}

__global__ void k_scanA(const int* __restrict__ cnt2, int* __restrict__ rp,
                        int* __restrict__ bsum) {
    __shared__ int sh[256];
    int t = threadIdx.x;
    int i = blockIdx.x * 256 + t;
    int v = (i < SEGS) ? cnt2[i] : 0;
    sh[t] = v;
    __syncthreads();
    for (int off = 1; off < 256; off <<= 1) {
        int u = (t >= off) ? sh[t - off] : 0;
        __syncthreads();
        sh[t] += u;
        __syncthreads();
    }
    if (i < SEGS) rp[i] = sh[t] - v;
    if (t == 255) bsum[blockIdx.x] = sh[255];
}

__global__ void k_scanB(int* __restrict__ bsum) {
    __shared__ int sh[256];
    int t = threadIdx.x;
    int loc[8];
    int s = 0;
#pragma unroll
    for (int i = 0; i < 8; i++) {
        int idx = t * 8 + i;
        int v = (idx < NBLK) ? bsum[idx] : 0;
        loc[i] = v;
        s += v;
    }
    sh[t] = s;
    __syncthreads();
    for (int off = 1; off < 256; off <<= 1) {
        int u = (t >= off) ? sh[t - off] : 0;
        __syncthreads();
        sh[t] += u;
        __syncthreads();
    }
    int run = sh[t] - s;
#pragma unroll
    for (int i = 0; i < 8; i++) {
        int idx = t * 8 + i;
        if (idx < NBLK) {
            int v = loc[i];
            bsum[idx] = run;
            run += v;
        }
    }
}

__global__ void k_scanC(int* __restrict__ rp, const int* __restrict__ bsum,
                        int* __restrict__ wo) {
    int i = blockIdx.x * 256 + threadIdx.x;
    if (i < SEGS) {
        int v = rp[i] + bsum[blockIdx.x];
        rp[i] = v;
        wo[i] = v;
    }
    if (i == 0) rp[SEGS] = EE;
}

// fill srcs (plain src ids, dst-major/relation-minor sorted) + per-edge scale 1/cnt
__global__ void k_fill(const int* __restrict__ src, const int* __restrict__ dst,
                       const int* __restrict__ et, const int* __restrict__ cnt2,
                       int* __restrict__ wo, int* __restrict__ srcs,
                       float* __restrict__ esc) {
    int e = blockIdx.x * 256 + threadIdx.x;
    if (e >= EE) return;
    int seg = dst[e] * RR + et[e];
    int pos = atomicAdd(&wo[seg], 1);
    srcs[pos] = src[e];
    esc[pos] = 1.f / (float)cnt2[seg];
}

// ==== compose column-concatenated weights: Wcat1[i][r*64+o], Wcat2[i][r*32+o] ====
__global__ void k_weights(const float* __restrict__ basis1, const float* __restrict__ comp1,
                          const float* __restrict__ basis2, const float* __restrict__ comp2,
                          float* __restrict__ Wcat1, float* __restrict__ Wcat2) {
    int idx = blockIdx.x * 256 + threadIdx.x;
    if (idx < RR * 64 * 64) {
        // Wcat1: [64][512]; idx = i*512 + r*64 + o
        int i = idx >> 9, rc = idx & 511;
        int r = rc >> 6, o = rc & 63;
        float acc = 0.f;
#pragma unroll
        for (int b = 0; b < 4; b++) acc += comp1[r * 4 + b] * basis1[b * 4096 + i * 64 + o];
        Wcat1[idx] = acc;
    } else if (idx < 2 * RR * 64 * 64) {
        // Wcat2: [128][256]; j = i*256 + r*32 + o
        int j = idx - RR * 64 * 64;
        int i = j >> 8, rc = j & 255;
        int r = rc >> 5, o = rc & 31;
        float acc = 0.f;
#pragma unroll
        for (int b = 0; b < 4; b++) acc += comp2[r * 4 + b] * basis2[b * 4096 + i * 32 + o];
        Wcat2[j] = acc;
    }
}

// ============ tiled GEMM: Y[tile 64 nodes][tile 64 cols] = X[n][K] @ B[K][M] ============
// grid.x = node tile, grid.y = mb (64-col block). Y addr = mb*mboff + n*ldY + c.
// LDS: Xs transposed [k][68], Ws [k][68]; thread = 4 nodes x 4 cols register block.
template <int KTOT>
__global__ __launch_bounds__(256) void k_gemm64(const float* __restrict__ X, int ldX,
                                                const float* __restrict__ B, int ldB,
                                                float* __restrict__ Y, int ldY,
                                                size_t mboff) {
    constexpr int Kc = (KTOT < 64) ? KTOT : 64;
    constexpr int KQ = Kc / 4;
    __shared__ __align__(16) float Xs[Kc * 68];
    __shared__ __align__(16) float Ws[Kc * 68];
    const int tid = threadIdx.x;
    const int tn4 = (tid >> 4) * 4;  // node offset in tile
    const int tm4 = (tid & 15) * 4;  // col offset in tile
    const int n0 = blockIdx.x * 64;
    const int mb = blockIdx.y;
    const float* Bm = B + (size_t)mb * 64;

    float acc[4][4];
#pragma unroll
    for (int a = 0; a < 4; a++)
#pragma unroll
        for (int b = 0; b < 4; b++) acc[a][b] = 0.f;

    for (int kk = 0; kk < KTOT; kk += Kc) {
        if (kk) __syncthreads();
        // stage X tile transposed: Xs[k][n], 64 nodes x Kc
        for (int i = tid; i < 64 * KQ; i += 256) {
            int nl = i / KQ, kq = i % KQ;
            float4 v = make_float4(0.f, 0.f, 0.f, 0.f);
            if (n0 + nl < NN)
                v = *reinterpret_cast<const float4*>(X + (size_t)(n0 + nl) * ldX + kk + 4 * kq);
            Xs[(4 * kq + 0) * 68 + nl] = v.x;
            Xs[(4 * kq + 1) * 68 + nl] = v.y;
            Xs[(4 * kq + 2) * 68 + nl] = v.z;
            Xs[(4 * kq + 3) * 68 + nl] = v.w;
        }
        // stage B tile: Ws[k][c], Kc x 64
        for (int i = tid; i < Kc * 16; i += 256) {
            int kl = i >> 4, cq = i & 15;
            float4 v = *reinterpret_cast<const float4*>(Bm + (size_t)(kk + kl) * ldB + 4 * cq);
            *reinterpret_cast<float4*>(&Ws[kl * 68 + 4 * cq]) = v;
        }
        __syncthreads();
#pragma unroll 4
        for (int k = 0; k < Kc; k++) {
            float4 xq = *reinterpret_cast<const float4*>(&Xs[k * 68 + tn4]);
            float4 wq = *reinterpret_cast<const float4*>(&Ws[k * 68 + tm4]);
            float xa[4] = {xq.x, xq.y, xq.z, xq.w};
            float wa[4] = {wq.x, wq.y, wq.z, wq.w};
#pragma unroll
            for (int a = 0; a < 4; a++)
#pragma unroll
                for (int b = 0; b < 4; b++) acc[a][b] += xa[a] * wa[b];
        }
    }
#pragma unroll
    for (int a = 0; a < 4; a++) {
        int n = n0 + tn4 + a;
        if (n < NN) {
            float4 v = make_float4(acc[a][0], acc[a][1], acc[a][2], acc[a][3]);
            *reinterpret_cast<float4*>(Y + (size_t)mb * mboff + (size_t)n * ldY + tm4) = v;
        }
    }
}

// ============ aggregate 1: per-node wave, nested per-relation loop, esc weights ============
// (byte-identical to R6)
__global__ __launch_bounds__(256) void k_agg1(const int* __restrict__ rp,
                                              const int* __restrict__ srcs,
                                              const float* __restrict__ esc,
                                              const float* __restrict__ y,
                                              const float* __restrict__ X,
                                              const float* __restrict__ root,
                                              const float* __restrict__ bias,
                                              float* __restrict__ x1,
                                              int r0, int nrel) {
    int wid = threadIdx.x >> 6, lane = threadIdx.x & 63;
    int n = blockIdx.x * 4 + wid;
    if (n >= NN) return;
    float acc = (r0 == 0) ? 0.f : x1[(size_t)n * 64 + lane];
    for (int rr = 0; rr < nrel; rr++) {
        int beg = rp[n * RR + r0 + rr], end = rp[n * RR + r0 + rr + 1];
        const float* yr = y + (size_t)rr * NN * 64;
        int k = beg;
        for (; k + 2 <= end; k += 2) {
            int sa = srcs[k], sb = srcs[k + 1];
            float ea = esc[k], eb = esc[k + 1];
            float va = yr[(size_t)sa * 64 + lane];
            float vb = yr[(size_t)sb * 64 + lane];
            acc += va * ea + vb * eb;
        }
        if (k < end) acc += yr[(size_t)srcs[k] * 64 + lane] * esc[k];
    }
    if (r0 + nrel == RR) {
        float xv = X[(size_t)n * 64 + lane];
        float rsum = bias[lane];
#pragma unroll 16
        for (int i = 0; i < 64; i++) rsum += __shfl(xv, i) * root[i * 64 + lane];
        x1[(size_t)n * 64 + lane] = fmaxf(acc + rsum, 0.f);
    } else {
        x1[(size_t)n * 64 + lane] = acc;
    }
}

// ============ aggregate 2: per-node wave; y layout now [rr>>1][n][64] + (rr&1)*32 ============
__global__ __launch_bounds__(256) void k_agg2(const int* __restrict__ rp,
                                              const int* __restrict__ srcs,
                                              const float* __restrict__ esc,
                                              const float* __restrict__ y,
                                              const float* __restrict__ X2,
                                              const float* __restrict__ root,
                                              const float* __restrict__ bias,
                                              float* __restrict__ x3,
                                              int r0, int nrel) {
    int wid = threadIdx.x >> 6, lane = threadIdx.x & 63;
    int n = blockIdx.x * 4 + wid;
    if (n >= NN) return;
    const int ol = lane & 31;
    float acc = (r0 == 0) ? 0.f : x3[(size_t)n * 32 + ol];
    for (int rr = 0; rr < nrel; rr++) {
        int gr = r0 + rr;
        int beg = rp[n * RR + gr], end = rp[n * RR + gr + 1];
        const float* yr = y + (size_t)(gr >> 1) * NN * 64 + (size_t)(gr & 1) * 32;
        int k = beg;
        for (; k + 2 <= end; k += 2) {
            int sa = srcs[k], sb = srcs[k + 1];
            float ea = esc[k], eb = esc[k + 1];
            float va = yr[(size_t)sa * 64 + ol];
            float vb = yr[(size_t)sb * 64 + ol];
            acc += va * ea + vb * eb;
        }
        if (k < end) acc += yr[(size_t)srcs[k] * 64 + ol] * esc[k];
    }
    if (r0 + nrel == RR) {
        float xvA = X2[(size_t)n * 128 + lane];
        float xvB = X2[(size_t)n * 128 + 64 + lane];
        float rsum = bias[ol];
#pragma unroll 16
        for (int i = 0; i < 64; i++) rsum += __shfl(xvA, i) * root[i * 32 + ol];
#pragma unroll 16
        for (int i = 0; i < 64; i++) rsum += __shfl(xvB, i) * root[(64 + i) * 32 + ol];
        if (lane < 32) x3[(size_t)n * 32 + ol] = fmaxf(acc + rsum, 0.f);
    } else {
        if (lane < 32) x3[(size_t)n * 32 + ol] = acc;
    }
}

// ===================== attention logits =====================
__global__ void k_gat_al(const float* __restrict__ h, const float* __restrict__ a_src,
                         const float* __restrict__ a_dst, float* __restrict__ als,
                         float* __restrict__ ald, int C) {
    int i = blockIdx.x * 256 + threadIdx.x;  // i = n*4 + hh
    if (i >= NN * 4) return;
    int hh = i & 3;
    const float* hp = h + (size_t)i * C;
    float a = 0.f, b = 0.f;
    for (int c = 0; c < C; c++) {
        float v = hp[c];
        a += v * a_src[hh * C + c];
        b += v * a_dst[hh * C + c];
    }
    als[i] = a;
    ald[i] = b;
}

// ============ fused per-dst GAT, one pass (logits O(1): no max needed), unroll-4 ============
// (byte-identical to R4/R6 passing kernel)
template <int HC, int C, bool MEANOUT>
__global__ __launch_bounds__(256) void k_gat(const int* __restrict__ rp,
                                             const int* __restrict__ srcs,
                                             const float* __restrict__ als,
                                             const float* __restrict__ ald,
                                             const float* __restrict__ h,
                                             const float* __restrict__ bias,
                                             float* __restrict__ out) {
    int wid = threadIdx.x >> 6, lane = threadIdx.x & 63;
    int n = blockIdx.x * 4 + wid;
    if (n >= NN) return;
    constexpr bool TWO = (HC == 128);
    const int hh0 = lane / C;
    const int hh1 = TWO ? (2 + lane / C) : 0;
    float aldd0 = ald[n * 4 + hh0];
    float z0 = __expf(leaky(als[n * 4 + hh0] + aldd0));
    float acc0 = z0 * h[(size_t)n * HC + lane];
    float aldd1 = 0.f, z1 = 0.f, acc1 = 0.f;
    if (TWO) {
        aldd1 = ald[n * 4 + hh1];
        z1 = __expf(leaky(als[n * 4 + hh1] + aldd1));
        acc1 = z1 * h[(size_t)n * HC + 64 + lane];
    }
    int beg = rp[n * RR], end = rp[n * RR + RR];
    int k = beg;
    for (; k + 4 <= end; k += 4) {
        int s[4];
#pragma unroll
        for (int u = 0; u < 4; u++) s[u] = srcs[k + u];
        float q0[4], q1[4], hv0[4], hv1[4];
#pragma unroll
        for (int u = 0; u < 4; u++) q0[u] = als[s[u] * 4 + hh0];
        if (TWO) {
#pragma unroll
            for (int u = 0; u < 4; u++) q1[u] = als[s[u] * 4 + hh1];
        }
#pragma unroll
        for (int u = 0; u < 4; u++) hv0[u] = h[(size_t)s[u] * HC + lane];
        if (TWO) {
#pragma unroll
            for (int u = 0; u < 4; u++) hv1[u] = h[(size_t)s[u] * HC + 64 + lane];
        }
#pragma unroll
        for (int u = 0; u < 4; u++) {
            float p0 = __expf(leaky(q0[u] + aldd0));
            z0 += p0;
            acc0 += p0 * hv0[u];
            if (TWO) {
                float p1 = __expf(leaky(q1[u] + aldd1));
                z1 += p1;
                acc1 += p1 * hv1[u];
            }
        }
    }
    for (; k < end; k++) {
        int s = srcs[k];
        float p0 = __expf(leaky(als[s * 4 + hh0] + aldd0));
        z0 += p0;
        acc0 += p0 * h[(size_t)s * HC + lane];
        if (TWO) {
            float p1 = __expf(leaky(als[s * 4 + hh1] + aldd1));
            z1 += p1;
            acc1 += p1 * h[(size_t)s * HC + 64 + lane];
        }
    }
    if (!MEANOUT) {
        out[(size_t)n * HC + lane] = acc0 / z0 + bias[lane];
        if (TWO) out[(size_t)n * HC + 64 + lane] = acc1 / z1 + bias[64 + lane];
    } else {
        float v = acc0 / z0;
        v += __shfl_xor(v, 16);
        v += __shfl_xor(v, 32);
        if (lane < 16) {
            float o2 = 0.25f * v + bias[lane];
            o2 = fmaxf(o2, 0.f);
            out[n * 16 + lane] = tanhf(o2);
        }
    }
}

extern "C" void kernel_launch(void* const* d_in, const int* in_sizes, int n_in,
                              void* d_out, int out_size, void* d_ws, size_t ws_size,
                              hipStream_t stream) {
    const float* x      = (const float*)d_in[0];
    const int*   ei     = (const int*)d_in[1];
    const int*   et     = (const int*)d_in[2];
    const float* basis1 = (const float*)d_in[3];
    const float* comp1  = (const float*)d_in[4];
    const float* root1  = (const float*)d_in[5];
    const float* brg1   = (const float*)d_in[6];
    const float* wg1    = (const float*)d_in[7];
    const float* asrc1  = (const float*)d_in[8];
    const float* adst1  = (const float*)d_in[9];
    const float* bg1    = (const float*)d_in[10];
    const float* basis2 = (const float*)d_in[11];
    const float* comp2  = (const float*)d_in[12];
    const float* root2  = (const float*)d_in[13];
    const float* brg2   = (const float*)d_in[14];
    const float* wg2    = (const float*)d_in[15];
    const float* asrc2  = (const float*)d_in[16];
    const float* adst2  = (const float*)d_in[17];
    const float* bg2    = (const float*)d_in[18];
    const int* src = ei;
    const int* dst = ei + EE;
    float* out = (float*)d_out;

    // ---- int region ----
    int* wsi = (int*)d_ws;
    size_t ioff = 0;
    auto ialloc = [&](size_t n) { int* p = wsi + ioff; ioff += (n + 3) & ~(size_t)3; return p; };
    int* cnt2 = ialloc(SEGS);
    int* rp   = ialloc(SEGS + 1);
    int* wo   = ialloc(SEGS + 1);
    int* bsum = ialloc(2048);
    int* srcs = ialloc(EE);
    // ---- float region ----
    float* wsf = (float*)(wsi + ioff);
    size_t total_f = (ws_size - ioff * sizeof(int)) / sizeof(float);
    const int nrel1 = 4;  // layer-1 relations per pass (ybuf = 4*NN*64 floats)
    size_t ybuf_f = (size_t)nrel1 * NN * 64;  // == 8*NN*32 (layer-3 single pass); >= NN*128 (h1)
    size_t need_f = (size_t)EE + ybuf_f + (size_t)NN * 64 + (size_t)NN * 128
                  + 2 * (size_t)RR * 4096 + 2 * (size_t)NN * 4 + 64;
    if (total_f < need_f) return;  // loud fail: output stays zero
    size_t foff = 0;
    auto falloc = [&](size_t n) { float* p = wsf + foff; foff += (n + 3) & ~(size_t)3; return p; };
    float* esc   = falloc(EE);
    float* ybuf  = falloc(ybuf_f);
    float* x1    = falloc((size_t)NN * 64);   // also x3
    float* x2    = falloc((size_t)NN * 128);  // also h2
    float* Wcat1 = falloc((size_t)RR * 4096); // [64][512]
    float* Wcat2 = falloc((size_t)RR * 4096); // [128][256]
    float* als   = falloc((size_t)NN * 4);
    float* ald   = falloc((size_t)NN * 4);
    float* h1 = ybuf;  // alias: ybuf dead between last agg1 and trans2
    float* x3 = x1;    // alias: x1 dead after dense1
    float* h2 = x2;    // alias: x2 dead after trans2/agg2

    const int EB = (EE + 255) / 256;
    const int NB4 = (NN + 3) / 4;      // one node per wave
    const int NT = (NN + 63) / 64;     // gemm node tiles (782)

    // ---- CSR build (dst,relation)-sorted ----
    hipMemsetAsync(cnt2, 0, SEGS * sizeof(int), stream);
    k_count2<<<EB, 256, 0, stream>>>(dst, et, cnt2);
    k_scanA<<<NBLK, 256, 0, stream>>>(cnt2, rp, bsum);
    k_scanB<<<1, 256, 0, stream>>>(bsum);
    k_scanC<<<NBLK, 256, 0, stream>>>(rp, bsum, wo);
    k_fill<<<EB, 256, 0, stream>>>(src, dst, et, cnt2, wo, srcs, esc);
    k_weights<<<(2 * RR * 4096) / 256, 256, 0, stream>>>(basis1, comp1, basis2, comp2, Wcat1, Wcat2);

    // ---- layer 1: RGCN(64->64) + relu: GEMM transform -> gather, 2 passes of 4 rel ----
    for (int r0 = 0; r0 < RR; r0 += nrel1) {
        k_gemm64<64><<<dim3(NT, nrel1), 256, 0, stream>>>(x, 64, Wcat1 + r0 * 64, 512,
                                                          ybuf, 64, (size_t)NN * 64);
        k_agg1<<<NB4, 256, 0, stream>>>(rp, srcs, esc, ybuf, x, root1, brg1, x1, r0, nrel1);
    }

    // ---- layer 2: GAT(64 -> 4x32 concat) ----
    k_gemm64<64><<<dim3(NT, 2), 256, 0, stream>>>(x1, 64, wg1, 128, h1, 128, 64);
    k_gat_al<<<(NN * 4 + 255) / 256, 256, 0, stream>>>(h1, asrc1, adst1, als, ald, 32);
    k_gat<128, 32, false><<<NB4, 256, 0, stream>>>(rp, srcs, als, ald, h1, bg1, x2);

    // ---- layer 3: RGCN(128->32) + relu: GEMM transform (single pass, 8 rel) -> gather ----
    k_gemm64<128><<<dim3(NT, 4), 256, 0, stream>>>(x2, 128, Wcat2, 256,
                                                   ybuf, 64, (size_t)NN * 64);
    k_agg2<<<NB4, 256, 0, stream>>>(rp, srcs, esc, ybuf, x2, root2, brg2, x3, 0, RR);

    // ---- layer 4: GAT(32 -> 4x16, mean heads) + relu + tanh ----
    k_gemm64<32><<<dim3(NT, 1), 256, 0, stream>>>(x3, 32, wg2, 64, h2, 64, 0);
    k_gat_al<<<(NN * 4 + 255) / 256, 256, 0, stream>>>(h2, asrc2, adst2, als, ald, 16);
    k_gat<64, 16, true><<<NB4, 256, 0, stream>>>(rp, srcs, als, ald, h2, bg2, out);
}

// Round 8
// 637.865 us; speedup vs baseline: 2.1319x; 1.0767x over previous
//
#include <hip/hip_runtime.h>
#include <math.h>

#define NN 50000
#define EE 800000
#define RR 8
#define SLOPE 0.2f
#define SEGS (NN * RR)            /* 400000 per-(node,relation) segments */
#define NBLK ((SEGS + 255) / 256) /* 1563 scan blocks */

__device__ __forceinline__ float leaky(float v) { return v >= 0.f ? v : SLOPE * v; }

__device__ __forceinline__ void fmacc(float4& a, const float4& v, float p) {
    a.x = fmaf(v.x, p, a.x);
    a.y = fmaf(v.y, p, a.y);
    a.z = fmaf(v.z, p, a.z);
    a.w = fmaf(v.w, p, a.w);
}

__device__ __forceinline__ void red4(float4& a, int m) {
    a.x += __shfl_xor(a.x, m);
    a.y += __shfl_xor(a.y, m);
    a.z += __shfl_xor(a.z, m);
    a.w += __shfl_xor(a.w, m);
}

// ============================ CSR build ============================
__global__ void k_count2(const int* __restrict__ dst, const int* __restrict__ et,
                         int* __restrict__ cnt2) {
    int e = blockIdx.x * 256 + threadIdx.x;
    if (e < EE) atomicAdd(&cnt2[dst[e] * RR + et[e]], 1);
}

__global__ void k_scanA(const int* __restrict__ cnt2, int* __restrict__ rp,
                        int* __restrict__ bsum) {
    __shared__ int sh[256];
    int t = threadIdx.x;
    int i = blockIdx.x * 256 + t;
    int v = (i < SEGS) ? cnt2[i] : 0;
    sh[t] = v;
    __syncthreads();
    for (int off = 1; off < 256; off <<= 1) {
        int u = (t >= off) ? sh[t - off] : 0;
        __syncthreads();
        sh[t] += u;
        __syncthreads();
    }
    if (i < SEGS) rp[i] = sh[t] - v;
    if (t == 255) bsum[blockIdx.x] = sh[255];
}

__global__ void k_scanB(int* __restrict__ bsum) {
    __shared__ int sh[256];
    int t = threadIdx.x;
    int loc[8];
    int s = 0;
#pragma unroll
    for (int i = 0; i < 8; i++) {
        int idx = t * 8 + i;
        int v = (idx < NBLK) ? bsum[idx] : 0;
        loc[i] = v;
        s += v;
    }
    sh[t] = s;
    __syncthreads();
    for (int off = 1; off < 256; off <<= 1) {
        int u = (t >= off) ? sh[t - off] : 0;
        __syncthreads();
        sh[t] += u;
        __syncthreads();
    }
    int run = sh[t] - s;
#pragma unroll
    for (int i = 0; i < 8; i++) {
        int idx = t * 8 + i;
        if (idx < NBLK) {
            int v = loc[i];
            bsum[idx] = run;
            run += v;
        }
    }
}

// writes row_ptr totals AND initializes fill cursors (wo aliases the dead cnt2)
__global__ void k_scanC(int* __restrict__ rp, const int* __restrict__ bsum,
                        int* __restrict__ wo) {
    int i = blockIdx.x * 256 + threadIdx.x;
    if (i < SEGS) {
        int v = rp[i] + bsum[blockIdx.x];
        rp[i] = v;
        wo[i] = v;
    }
    if (i == 0) rp[SEGS] = EE;
}

// fill srcs (dst-major/relation-minor sorted) + per-edge relation + per-edge 1/cnt
__global__ void k_fill(const int* __restrict__ src, const int* __restrict__ dst,
                       const int* __restrict__ et, const int* __restrict__ rp,
                       int* __restrict__ wo, int* __restrict__ srcs,
                       unsigned char* __restrict__ erel, float* __restrict__ esc) {
    int e = blockIdx.x * 256 + threadIdx.x;
    if (e >= EE) return;
    int r = et[e];
    int seg = dst[e] * RR + r;
    int pos = atomicAdd(&wo[seg], 1);
    srcs[pos] = src[e];
    erel[pos] = (unsigned char)r;
    esc[pos] = 1.f / (float)(rp[seg + 1] - rp[seg]);  // count >= 1 (this edge exists)
}

// ==== compose column-concatenated weights: Wcat1[i][r*64+o], Wcat2[i][r*32+o] ====
__global__ void k_weights(const float* __restrict__ basis1, const float* __restrict__ comp1,
                          const float* __restrict__ basis2, const float* __restrict__ comp2,
                          float* __restrict__ Wcat1, float* __restrict__ Wcat2) {
    int idx = blockIdx.x * 256 + threadIdx.x;
    if (idx < RR * 64 * 64) {
        int i = idx >> 9, rc = idx & 511;
        int r = rc >> 6, o = rc & 63;
        float acc = 0.f;
#pragma unroll
        for (int b = 0; b < 4; b++) acc += comp1[r * 4 + b] * basis1[b * 4096 + i * 64 + o];
        Wcat1[idx] = acc;
    } else if (idx < 2 * RR * 64 * 64) {
        int j = idx - RR * 64 * 64;
        int i = j >> 8, rc = j & 255;
        int r = rc >> 5, o = rc & 31;
        float acc = 0.f;
#pragma unroll
        for (int b = 0; b < 4; b++) acc += comp2[r * 4 + b] * basis2[b * 4096 + i * 32 + o];
        Wcat2[j] = acc;
    }
}

// ============ tiled GEMM (unchanged from R7) ============
template <int KTOT>
__global__ __launch_bounds__(256) void k_gemm64(const float* __restrict__ X, int ldX,
                                                const float* __restrict__ B, int ldB,
                                                float* __restrict__ Y, int ldY,
                                                size_t mboff) {
    constexpr int Kc = (KTOT < 64) ? KTOT : 64;
    constexpr int KQ = Kc / 4;
    __shared__ __align__(16) float Xs[Kc * 68];
    __shared__ __align__(16) float Ws[Kc * 68];
    const int tid = threadIdx.x;
    const int tn4 = (tid >> 4) * 4;
    const int tm4 = (tid & 15) * 4;
    const int n0 = blockIdx.x * 64;
    const int mb = blockIdx.y;
    const float* Bm = B + (size_t)mb * 64;

    float acc[4][4];
#pragma unroll
    for (int a = 0; a < 4; a++)
#pragma unroll
        for (int b = 0; b < 4; b++) acc[a][b] = 0.f;

    for (int kk = 0; kk < KTOT; kk += Kc) {
        if (kk) __syncthreads();
        for (int i = tid; i < 64 * KQ; i += 256) {
            int nl = i / KQ, kq = i % KQ;
            float4 v = make_float4(0.f, 0.f, 0.f, 0.f);
            if (n0 + nl < NN)
                v = *reinterpret_cast<const float4*>(X + (size_t)(n0 + nl) * ldX + kk + 4 * kq);
            Xs[(4 * kq + 0) * 68 + nl] = v.x;
            Xs[(4 * kq + 1) * 68 + nl] = v.y;
            Xs[(4 * kq + 2) * 68 + nl] = v.z;
            Xs[(4 * kq + 3) * 68 + nl] = v.w;
        }
        for (int i = tid; i < Kc * 16; i += 256) {
            int kl = i >> 4, cq = i & 15;
            float4 v = *reinterpret_cast<const float4*>(Bm + (size_t)(kk + kl) * ldB + 4 * cq);
            *reinterpret_cast<float4*>(&Ws[kl * 68 + 4 * cq]) = v;
        }
        __syncthreads();
#pragma unroll 4
        for (int k = 0; k < Kc; k++) {
            float4 xq = *reinterpret_cast<const float4*>(&Xs[k * 68 + tn4]);
            float4 wq = *reinterpret_cast<const float4*>(&Ws[k * 68 + tm4]);
            float xa[4] = {xq.x, xq.y, xq.z, xq.w};
            float wa[4] = {wq.x, wq.y, wq.z, wq.w};
#pragma unroll
            for (int a = 0; a < 4; a++)
#pragma unroll
                for (int b = 0; b < 4; b++) acc[a][b] += xa[a] * wa[b];
        }
    }
#pragma unroll
    for (int a = 0; a < 4; a++) {
        int n = n0 + tn4 + a;
        if (n < NN) {
            float4 v = make_float4(acc[a][0], acc[a][1], acc[a][2], acc[a][3]);
            *reinterpret_cast<float4*>(Y + (size_t)mb * mboff + (size_t)n * ldY + tm4) = v;
        }
    }
}

// ===== aggregate 1: 4 edge-groups x 16 lanes (float4 = 64-f rows), unroll-2 =====
// NB: grid covers NN exactly (NN % 4 == 0) so every thread reaches __syncthreads.
__global__ __launch_bounds__(256) void k_agg1(const int* __restrict__ rp,
                                              const int* __restrict__ srcs,
                                              const unsigned char* __restrict__ erel,
                                              const float* __restrict__ esc,
                                              const float* __restrict__ y,
                                              const float* __restrict__ X,
                                              const float* __restrict__ root,
                                              const float* __restrict__ bias,
                                              float* __restrict__ x1,
                                              int r0, int nrel) {
    int wid = threadIdx.x >> 6, lane = threadIdx.x & 63;
    int n = blockIdx.x * 4 + wid;
    int q = lane & 15;
    int beg = rp[n * RR + r0], end = rp[n * RR + r0 + nrel];
    float4 acc = make_float4(0.f, 0.f, 0.f, 0.f);
    int k = beg + (lane >> 4);
    for (; k + 4 < end; k += 8) {
        int s0 = srcs[k], s1 = srcs[k + 4];
        int ra = erel[k] - r0, rb = erel[k + 4] - r0;
        float e0 = esc[k], e1 = esc[k + 4];
        float4 v0 = *(const float4*)(y + ((size_t)ra * NN + s0) * 64 + q * 4);
        float4 v1 = *(const float4*)(y + ((size_t)rb * NN + s1) * 64 + q * 4);
        fmacc(acc, v0, e0);
        fmacc(acc, v1, e1);
    }
    if (k < end) {
        int s0 = srcs[k];
        int ra = erel[k] - r0;
        float4 v0 = *(const float4*)(y + ((size_t)ra * NN + s0) * 64 + q * 4);
        fmacc(acc, v0, esc[k]);
    }
    red4(acc, 16);
    red4(acc, 32);
    if (r0 + nrel < RR) {
        if (lane < 16) *(float4*)(x1 + (size_t)n * 64 + q * 4) = acc;  // partial
    } else {
        __shared__ float sh[4][64];
        if (lane < 16) {
            sh[wid][q * 4 + 0] = acc.x;
            sh[wid][q * 4 + 1] = acc.y;
            sh[wid][q * 4 + 2] = acc.z;
            sh[wid][q * 4 + 3] = acc.w;
        }
        __syncthreads();
        float av = sh[wid][lane];
        float prev = x1[(size_t)n * 64 + lane];
        float xv = X[(size_t)n * 64 + lane];
        float rsum = bias[lane];
#pragma unroll 16
        for (int i = 0; i < 64; i++) rsum += __shfl(xv, i) * root[i * 64 + lane];
        x1[(size_t)n * 64 + lane] = fmaxf(av + prev + rsum, 0.f);
    }
}

// ===== aggregate 2: 8 edge-groups x 8 lanes (float4 = 32-f rows), unroll-2 =====
__global__ __launch_bounds__(256) void k_agg2(const int* __restrict__ rp,
                                              const int* __restrict__ srcs,
                                              const unsigned char* __restrict__ erel,
                                              const float* __restrict__ esc,
                                              const float* __restrict__ y,
                                              const float* __restrict__ X2,
                                              const float* __restrict__ root,
                                              const float* __restrict__ bias,
                                              float* __restrict__ x3) {
    int wid = threadIdx.x >> 6, lane = threadIdx.x & 63;
    int n = blockIdx.x * 4 + wid;
    int q = lane & 7;
    int beg = rp[n * RR], end = rp[n * RR + RR];
    float4 acc = make_float4(0.f, 0.f, 0.f, 0.f);
    int k = beg + (lane >> 3);
    for (; k + 8 < end; k += 16) {
        int s0 = srcs[k], s1 = srcs[k + 8];
        int g0 = erel[k], g1 = erel[k + 8];
        float e0 = esc[k], e1 = esc[k + 8];
        float4 v0 = *(const float4*)(y + ((size_t)(g0 >> 1) * NN + s0) * 64 + (g0 & 1) * 32 + q * 4);
        float4 v1 = *(const float4*)(y + ((size_t)(g1 >> 1) * NN + s1) * 64 + (g1 & 1) * 32 + q * 4);
        fmacc(acc, v0, e0);
        fmacc(acc, v1, e1);
    }
    if (k < end) {
        int s0 = srcs[k];
        int g0 = erel[k];
        float4 v0 = *(const float4*)(y + ((size_t)(g0 >> 1) * NN + s0) * 64 + (g0 & 1) * 32 + q * 4);
        fmacc(acc, v0, esc[k]);
    }
    red4(acc, 8);
    red4(acc, 16);
    red4(acc, 32);
    __shared__ float sh[4][32];
    if (lane < 8) {
        sh[wid][q * 4 + 0] = acc.x;
        sh[wid][q * 4 + 1] = acc.y;
        sh[wid][q * 4 + 2] = acc.z;
        sh[wid][q * 4 + 3] = acc.w;
    }
    __syncthreads();
    int ol = lane & 31;
    float av = sh[wid][ol];
    float xvA = X2[(size_t)n * 128 + lane];
    float xvB = X2[(size_t)n * 128 + 64 + lane];
    float rsum = bias[ol];
#pragma unroll 16
    for (int i = 0; i < 64; i++) rsum += __shfl(xvA, i) * root[i * 32 + ol];
#pragma unroll 16
    for (int i = 0; i < 64; i++) rsum += __shfl(xvB, i) * root[(64 + i) * 32 + ol];
    if (lane < 32) x3[(size_t)n * 32 + ol] = fmaxf(av + rsum, 0.f);
}

// ===================== attention logits (unchanged) =====================
__global__ void k_gat_al(const float* __restrict__ h, const float* __restrict__ a_src,
                         const float* __restrict__ a_dst, float* __restrict__ als,
                         float* __restrict__ ald, int C) {
    int i = blockIdx.x * 256 + threadIdx.x;  // i = n*4 + hh
    if (i >= NN * 4) return;
    int hh = i & 3;
    const float* hp = h + (size_t)i * C;
    float a = 0.f, b = 0.f;
    for (int c = 0; c < C; c++) {
        float v = hp[c];
        a += v * a_src[hh * C + c];
        b += v * a_dst[hh * C + c];
    }
    als[i] = a;
    ald[i] = b;
}

// ===== fused per-dst GAT, vectorized: HC/4 lanes per edge-group, float4 rows =====
template <int HC, int C, bool MEANOUT>
__global__ __launch_bounds__(256) void k_gat(const int* __restrict__ rp,
                                             const int* __restrict__ srcs,
                                             const float* __restrict__ als,
                                             const float* __restrict__ ald,
                                             const float* __restrict__ h,
                                             const float* __restrict__ bias,
                                             float* __restrict__ out) {
    constexpr int G = HC / 4;   // lanes per edge-group (32 or 16)
    constexpr int NG = 64 / G;  // edge-groups per wave (2 or 4)
    int wid = threadIdx.x >> 6, lane = threadIdx.x & 63;
    int n = blockIdx.x * 4 + wid;
    if (n >= NN) return;
    int g = lane / G, q = lane % G;
    int hh = (q * 4) / C;  // head of this lane's channel quad
    float aldd = ald[n * 4 + hh];
    float4 acc = make_float4(0.f, 0.f, 0.f, 0.f);
    float z = 0.f;
    if (g == 0) {  // self-loop, counted once
        float p = __expf(leaky(als[n * 4 + hh] + aldd));
        float4 hv = *(const float4*)(h + (size_t)n * HC + q * 4);
        z = p;
        fmacc(acc, hv, p);
    }
    int beg = rp[n * RR], end = rp[n * RR + RR];
    int k = beg + g;
    for (; k + NG < end; k += 2 * NG) {
        int s0 = srcs[k], s1 = srcs[k + NG];
        float a0 = als[s0 * 4 + hh], a1 = als[s1 * 4 + hh];
        float4 h0 = *(const float4*)(h + (size_t)s0 * HC + q * 4);
        float4 h1 = *(const float4*)(h + (size_t)s1 * HC + q * 4);
        float p0 = __expf(leaky(a0 + aldd));
        float p1 = __expf(leaky(a1 + aldd));
        z += p0 + p1;
        fmacc(acc, h0, p0);
        fmacc(acc, h1, p1);
    }
    if (k < end) {
        int s0 = srcs[k];
        float p0 = __expf(leaky(als[s0 * 4 + hh] + aldd));
        float4 h0 = *(const float4*)(h + (size_t)s0 * HC + q * 4);
        z += p0;
        fmacc(acc, h0, p0);
    }
    if (NG == 4) {
        red4(acc, 16);
        z += __shfl_xor(z, 16);
    }
    red4(acc, 32);
    z += __shfl_xor(z, 32);
    float inv = 1.f / z;
    float4 o = make_float4(acc.x * inv, acc.y * inv, acc.z * inv, acc.w * inv);
    if (!MEANOUT) {
        if (g == 0) {
            float4 b = *(const float4*)(bias + q * 4);
            o.x += b.x; o.y += b.y; o.z += b.z; o.w += b.w;
            *(float4*)(out + (size_t)n * HC + q * 4) = o;
        }
    } else {
        // heads live at q, q^4, q^8, q^12 (head = q>>2): sum then mean
        red4(o, 4);
        red4(o, 8);
        if (lane < 4) {
            float4 b = *(const float4*)(bias + lane * 4);
            float4 r;
            r.x = tanhf(fmaxf(0.25f * o.x + b.x, 0.f));
            r.y = tanhf(fmaxf(0.25f * o.y + b.y, 0.f));
            r.z = tanhf(fmaxf(0.25f * o.z + b.z, 0.f));
            r.w = tanhf(fmaxf(0.25f * o.w + b.w, 0.f));
            *(float4*)(out + (size_t)n * 16 + lane * 4) = r;
        }
    }
}

extern "C" void kernel_launch(void* const* d_in, const int* in_sizes, int n_in,
                              void* d_out, int out_size, void* d_ws, size_t ws_size,
                              hipStream_t stream) {
    const float* x      = (const float*)d_in[0];
    const int*   ei     = (const int*)d_in[1];
    const int*   et     = (const int*)d_in[2];
    const float* basis1 = (const float*)d_in[3];
    const float* comp1  = (const float*)d_in[4];
    const float* root1  = (const float*)d_in[5];
    const float* brg1   = (const float*)d_in[6];
    const float* wg1    = (const float*)d_in[7];
    const float* asrc1  = (const float*)d_in[8];
    const float* adst1  = (const float*)d_in[9];
    const float* bg1    = (const float*)d_in[10];
    const float* basis2 = (const float*)d_in[11];
    const float* comp2  = (const float*)d_in[12];
    const float* root2  = (const float*)d_in[13];
    const float* brg2   = (const float*)d_in[14];
    const float* wg2    = (const float*)d_in[15];
    const float* asrc2  = (const float*)d_in[16];
    const float* adst2  = (const float*)d_in[17];
    const float* bg2    = (const float*)d_in[18];
    const int* src = ei;
    const int* dst = ei + EE;
    float* out = (float*)d_out;

    // ---- int region ----
    int* wsi = (int*)d_ws;
    size_t ioff = 0;
    auto ialloc = [&](size_t n) { int* p = wsi + ioff; ioff += (n + 3) & ~(size_t)3; return p; };
    int* cnt2 = ialloc(SEGS);      // reused as fill cursors (wo) after scanC
    int* rp   = ialloc(SEGS + 1);
    int* bsum = ialloc(2048);
    int* srcs = ialloc(EE);
    unsigned char* erel = (unsigned char*)ialloc((EE + 3) / 4);
    int* wo = cnt2;
    // ---- float region ----
    float* wsf = (float*)(wsi + ioff);
    size_t total_f = (ws_size - ioff * sizeof(int)) / sizeof(float);
    const int nrel1 = 4;  // layer-1 relations per pass
    size_t ybuf_f = (size_t)nrel1 * NN * 64;  // also = 8*NN*32 for layer 3; >= NN*128 (h1 alias)
    size_t need_f = (size_t)EE + ybuf_f + (size_t)NN * 64 + (size_t)NN * 128
                  + 2 * (size_t)RR * 4096 + 2 * (size_t)NN * 4 + 64;
    if (total_f < need_f) return;  // loud fail: output stays zero
    size_t foff = 0;
    auto falloc = [&](size_t n) { float* p = wsf + foff; foff += (n + 3) & ~(size_t)3; return p; };
    float* esc   = falloc(EE);
    float* ybuf  = falloc(ybuf_f);
    float* x1    = falloc((size_t)NN * 64);   // also x3
    float* x2    = falloc((size_t)NN * 128);  // also h2
    float* Wcat1 = falloc((size_t)RR * 4096); // [64][512]
    float* Wcat2 = falloc((size_t)RR * 4096); // [128][256]
    float* als   = falloc((size_t)NN * 4);
    float* ald   = falloc((size_t)NN * 4);
    float* h1 = ybuf;  // alias: ybuf dead between last agg1 and trans2
    float* x3 = x1;    // alias: x1 dead after dense1
    float* h2 = x2;    // alias: x2 dead after trans2/agg2

    const int EB = (EE + 255) / 256;
    const int NB4 = (NN + 3) / 4;   // one node per wave; NN % 4 == 0 -> exact
    const int NT = (NN + 63) / 64;  // gemm node tiles

    // ---- CSR build (dst,relation)-sorted ----
    hipMemsetAsync(cnt2, 0, SEGS * sizeof(int), stream);
    k_count2<<<EB, 256, 0, stream>>>(dst, et, cnt2);
    k_scanA<<<NBLK, 256, 0, stream>>>(cnt2, rp, bsum);
    k_scanB<<<1, 256, 0, stream>>>(bsum);
    k_scanC<<<NBLK, 256, 0, stream>>>(rp, bsum, wo);
    k_fill<<<EB, 256, 0, stream>>>(src, dst, et, rp, wo, srcs, erel, esc);
    k_weights<<<(2 * RR * 4096) / 256, 256, 0, stream>>>(basis1, comp1, basis2, comp2, Wcat1, Wcat2);

    // ---- layer 1: RGCN(64->64) + relu: GEMM transform -> vector gather, 2 passes ----
    for (int r0 = 0; r0 < RR; r0 += nrel1) {
        k_gemm64<64><<<dim3(NT, nrel1), 256, 0, stream>>>(x, 64, Wcat1 + r0 * 64, 512,
                                                          ybuf, 64, (size_t)NN * 64);
        k_agg1<<<NB4, 256, 0, stream>>>(rp, srcs, erel, esc, ybuf, x, root1, brg1, x1, r0, nrel1);
    }

    // ---- layer 2: GAT(64 -> 4x32 concat) ----
    k_gemm64<64><<<dim3(NT, 2), 256, 0, stream>>>(x1, 64, wg1, 128, h1, 128, 64);
    k_gat_al<<<(NN * 4 + 255) / 256, 256, 0, stream>>>(h1, asrc1, adst1, als, ald, 32);
    k_gat<128, 32, false><<<NB4, 256, 0, stream>>>(rp, srcs, als, ald, h1, bg1, x2);

    // ---- layer 3: RGCN(128->32) + relu: GEMM transform (8 rel packed) -> vector gather ----
    k_gemm64<128><<<dim3(NT, 4), 256, 0, stream>>>(x2, 128, Wcat2, 256,
                                                   ybuf, 64, (size_t)NN * 64);
    k_agg2<<<NB4, 256, 0, stream>>>(rp, srcs, erel, esc, ybuf, x2, root2, brg2, x3);

    // ---- layer 4: GAT(32 -> 4x16, mean heads) + relu + tanh ----
    k_gemm64<32><<<dim3(NT, 1), 256, 0, stream>>>(x3, 32, wg2, 64, h2, 64, 0);
    k_gat_al<<<(NN * 4 + 255) / 256, 256, 0, stream>>>(h2, asrc2, adst2, als, ald, 16);
    k_gat<64, 16, true><<<NB4, 256, 0, stream>>>(rp, srcs, als, ald, h2, bg2, out);
}

// Round 9
// 574.917 us; speedup vs baseline: 2.3653x; 1.1095x over previous
//
#include <hip/hip_runtime.h>
#include <math.h>

#define NN 50000
#define EE 800000
#define RR 8
#define SLOPE 0.2f
#define SEGS (NN * RR)            /* 400000 per-(node,relation) segments */
#define NBLK ((SEGS + 255) / 256) /* 1563 scan blocks */

__device__ __forceinline__ float leaky(float v) { return v >= 0.f ? v : SLOPE * v; }

__device__ __forceinline__ void fmacc(float4& a, const float4& v, float p) {
    a.x = fmaf(v.x, p, a.x);
    a.y = fmaf(v.y, p, a.y);
    a.z = fmaf(v.z, p, a.z);
    a.w = fmaf(v.w, p, a.w);
}

__device__ __forceinline__ void red4(float4& a, int m) {
    a.x += __shfl_xor(a.x, m);
    a.y += __shfl_xor(a.y, m);
    a.z += __shfl_xor(a.z, m);
    a.w += __shfl_xor(a.w, m);
}

// ============================ CSR build (proven R8 structure) ============================
__global__ void k_count2(const int* __restrict__ dst, const int* __restrict__ et,
                         int* __restrict__ cnt2) {
    int e = blockIdx.x * 256 + threadIdx.x;
    if (e < EE) atomicAdd(&cnt2[dst[e] * RR + et[e]], 1);
}

__global__ void k_scanA(const int* __restrict__ cnt2, int* __restrict__ rp,
                        int* __restrict__ bsum) {
    __shared__ int sh[256];
    int t = threadIdx.x;
    int i = blockIdx.x * 256 + t;
    int v = (i < SEGS) ? cnt2[i] : 0;
    sh[t] = v;
    __syncthreads();
    for (int off = 1; off < 256; off <<= 1) {
        int u = (t >= off) ? sh[t - off] : 0;
        __syncthreads();
        sh[t] += u;
        __syncthreads();
    }
    if (i < SEGS) rp[i] = sh[t] - v;
    if (t == 255) bsum[blockIdx.x] = sh[255];
}

__global__ void k_scanB(int* __restrict__ bsum) {
    __shared__ int sh[256];
    int t = threadIdx.x;
    int loc[8];
    int s = 0;
#pragma unroll
    for (int i = 0; i < 8; i++) {
        int idx = t * 8 + i;
        int v = (idx < NBLK) ? bsum[idx] : 0;
        loc[i] = v;
        s += v;
    }
    sh[t] = s;
    __syncthreads();
    for (int off = 1; off < 256; off <<= 1) {
        int u = (t >= off) ? sh[t - off] : 0;
        __syncthreads();
        sh[t] += u;
        __syncthreads();
    }
    int run = sh[t] - s;
#pragma unroll
    for (int i = 0; i < 8; i++) {
        int idx = t * 8 + i;
        if (idx < NBLK) {
            int v = loc[i];
            bsum[idx] = run;
            run += v;
        }
    }
}

__global__ void k_scanC(int* __restrict__ rp, const int* __restrict__ bsum,
                        int* __restrict__ wo) {
    int i = blockIdx.x * 256 + threadIdx.x;
    if (i < SEGS) {
        int v = rp[i] + bsum[blockIdx.x];
        rp[i] = v;
        wo[i] = v;
    }
    if (i == 0) rp[SEGS] = EE;
}

__global__ void k_fill(const int* __restrict__ src, const int* __restrict__ dst,
                       const int* __restrict__ et, const int* __restrict__ rp,
                       int* __restrict__ wo, int* __restrict__ srcs,
                       unsigned char* __restrict__ erel, float* __restrict__ esc) {
    int e = blockIdx.x * 256 + threadIdx.x;
    if (e >= EE) return;
    int r = et[e];
    int seg = dst[e] * RR + r;
    int pos = atomicAdd(&wo[seg], 1);
    srcs[pos] = src[e];
    erel[pos] = (unsigned char)r;
    esc[pos] = 1.f / (float)(rp[seg + 1] - rp[seg]);
}

// ==== compose column-concatenated weights: Wcat1[i][r*64+o], Wcat2[i][r*32+o] ====
__global__ void k_weights(const float* __restrict__ basis1, const float* __restrict__ comp1,
                          const float* __restrict__ basis2, const float* __restrict__ comp2,
                          float* __restrict__ Wcat1, float* __restrict__ Wcat2) {
    int idx = blockIdx.x * 256 + threadIdx.x;
    if (idx < RR * 64 * 64) {
        int i = idx >> 9, rc = idx & 511;
        int r = rc >> 6, o = rc & 63;
        float acc = 0.f;
#pragma unroll
        for (int b = 0; b < 4; b++) acc += comp1[r * 4 + b] * basis1[b * 4096 + i * 64 + o];
        Wcat1[idx] = acc;
    } else if (idx < 2 * RR * 64 * 64) {
        int j = idx - RR * 64 * 64;
        int i = j >> 8, rc = j & 255;
        int r = rc >> 5, o = rc & 31;
        float acc = 0.f;
#pragma unroll
        for (int b = 0; b < 4; b++) acc += comp2[r * 4 + b] * basis2[b * 4096 + i * 32 + o];
        Wcat2[j] = acc;
    }
}

// ==== prep: padded per-head / stacked / root weights + logit projection vectors ====
// wg1r [4][64][64] (cols 32-63 zero), Wstk [128][64] (cols 16-63 zero),
// Wr2p [128][64] (cols 32-63 zero), U1 [64][8], U2 [32][8]
__global__ void k_prep(const float* __restrict__ wg1, const float* __restrict__ wg2,
                       const float* __restrict__ root2,
                       const float* __restrict__ asrc1, const float* __restrict__ adst1,
                       const float* __restrict__ asrc2, const float* __restrict__ adst2,
                       float* __restrict__ wg1r, float* __restrict__ Wstk,
                       float* __restrict__ Wr2p, float* __restrict__ U1,
                       float* __restrict__ U2) {
    int idx = blockIdx.x * 256 + threadIdx.x;
    if (idx < 16384) {  // wg1r[h][k][c]
        int h = idx >> 12, kc = idx & 4095;
        int k = kc >> 6, c = kc & 63;
        wg1r[idx] = (c < 32) ? wg1[k * 128 + h * 32 + c] : 0.f;
    } else if (idx < 16384 + 8192) {  // Wstk[h*32+k][c] = wg2[k][h*16+c]
        int j = idx - 16384;
        int row = j >> 6, c = j & 63;
        int h = row >> 5, k = row & 31;
        Wstk[j] = (c < 16) ? wg2[k * 64 + h * 16 + c] : 0.f;
    } else if (idx < 16384 + 8192 + 8192) {  // Wr2p[k][c]
        int j = idx - 16384 - 8192;
        int k = j >> 6, c = j & 63;
        Wr2p[j] = (c < 32) ? root2[k * 32 + c] : 0.f;
    } else if (idx < 16384 + 8192 + 8192 + 512) {  // U1[k][j] j<4:src h=j, j>=4:dst h=j-4
        int j0 = idx - 16384 - 8192 - 8192;
        int k = j0 >> 3, j = j0 & 7;
        int h = j & 3;
        const float* a = (j < 4) ? asrc1 : adst1;
        float s = 0.f;
        for (int c = 0; c < 32; c++) s += wg1[k * 128 + h * 32 + c] * a[h * 32 + c];
        U1[k * 8 + j] = s;
    } else if (idx < 16384 + 8192 + 8192 + 512 + 256) {  // U2[k][j]
        int j0 = idx - 16384 - 8192 - 8192 - 512;
        int k = j0 >> 3, j = j0 & 7;
        int h = j & 3;
        const float* a = (j < 4) ? asrc2 : adst2;
        float s = 0.f;
        for (int c = 0; c < 16; c++) s += wg2[k * 64 + h * 16 + c] * a[h * 16 + c];
        U2[k * 8 + j] = s;
    }
}

// ============ tiled GEMM, generalized (mb-strides for X/B/Y, optional bias, Mvalid) ============
// Y[mb*ymb + n*ldY + c] = sum_k X[n*ldX + mb*xmb + k] * B[mb*bmb + k*ldB + c] (+bias)
template <int KTOT, int MV = 64>
__global__ __launch_bounds__(256) void k_gemm64(const float* __restrict__ X, int ldX, int xmb,
                                                const float* __restrict__ B, int ldB, int bmb,
                                                float* __restrict__ Y, int ldY, size_t ymb,
                                                const float* __restrict__ bias, int biasmb) {
    constexpr int Kc = (KTOT < 64) ? KTOT : 64;
    constexpr int KQ = Kc / 4;
    __shared__ __align__(16) float Xs[Kc * 68];
    __shared__ __align__(16) float Ws[Kc * 68];
    const int tid = threadIdx.x;
    const int tn4 = (tid >> 4) * 4;
    const int tm4 = (tid & 15) * 4;
    const int n0 = blockIdx.x * 64;
    const int mb = blockIdx.y;
    const float* Bm = B + (size_t)mb * bmb;
    const float* Xm = X + (size_t)mb * xmb;

    float acc[4][4];
#pragma unroll
    for (int a = 0; a < 4; a++)
#pragma unroll
        for (int b = 0; b < 4; b++) acc[a][b] = 0.f;

    for (int kk = 0; kk < KTOT; kk += Kc) {
        if (kk) __syncthreads();
        for (int i = tid; i < 64 * KQ; i += 256) {
            int nl = i / KQ, kq = i % KQ;
            float4 v = make_float4(0.f, 0.f, 0.f, 0.f);
            if (n0 + nl < NN)
                v = *reinterpret_cast<const float4*>(Xm + (size_t)(n0 + nl) * ldX + kk + 4 * kq);
            Xs[(4 * kq + 0) * 68 + nl] = v.x;
            Xs[(4 * kq + 1) * 68 + nl] = v.y;
            Xs[(4 * kq + 2) * 68 + nl] = v.z;
            Xs[(4 * kq + 3) * 68 + nl] = v.w;
        }
        for (int i = tid; i < Kc * 16; i += 256) {
            int kl = i >> 4, cq = i & 15;
            float4 v = *reinterpret_cast<const float4*>(Bm + (size_t)(kk + kl) * ldB + 4 * cq);
            *reinterpret_cast<float4*>(&Ws[kl * 68 + 4 * cq]) = v;
        }
        __syncthreads();
#pragma unroll 4
        for (int k = 0; k < Kc; k++) {
            float4 xq = *reinterpret_cast<const float4*>(&Xs[k * 68 + tn4]);
            float4 wq = *reinterpret_cast<const float4*>(&Ws[k * 68 + tm4]);
            float xa[4] = {xq.x, xq.y, xq.z, xq.w};
            float wa[4] = {wq.x, wq.y, wq.z, wq.w};
#pragma unroll
            for (int a = 0; a < 4; a++)
#pragma unroll
                for (int b = 0; b < 4; b++) acc[a][b] += xa[a] * wa[b];
        }
    }
    if (MV == 64 || tm4 < MV) {
        float4 bv = make_float4(0.f, 0.f, 0.f, 0.f);
        if (bias) bv = *reinterpret_cast<const float4*>(bias + (size_t)mb * biasmb + tm4);
#pragma unroll
        for (int a = 0; a < 4; a++) {
            int n = n0 + tn4 + a;
            if (n < NN) {
                float4 v = make_float4(acc[a][0] + bv.x, acc[a][1] + bv.y,
                                       acc[a][2] + bv.z, acc[a][3] + bv.w);
                *reinterpret_cast<float4*>(Y + (size_t)mb * ymb + (size_t)n * ldY + tm4) = v;
            }
        }
    }
}

// ===== aggregate 1: 4 edge-groups x 16 lanes (float4, 64-f rows); x1 pre-holds x@root =====
__global__ __launch_bounds__(256) void k_agg1(const int* __restrict__ rp,
                                              const int* __restrict__ srcs,
                                              const unsigned char* __restrict__ erel,
                                              const float* __restrict__ esc,
                                              const float* __restrict__ y,
                                              const float* __restrict__ bias,
                                              float* __restrict__ x1,
                                              int r0, int nrel, int final_pass) {
    int wid = threadIdx.x >> 6, lane = threadIdx.x & 63;
    int n = blockIdx.x * 4 + wid;
    int q = lane & 15;
    int beg = rp[n * RR + r0], end = rp[n * RR + r0 + nrel];
    float4 acc = make_float4(0.f, 0.f, 0.f, 0.f);
    int k = beg + (lane >> 4);
    for (; k + 4 < end; k += 8) {
        int s0 = srcs[k], s1 = srcs[k + 4];
        int ra = erel[k] - r0, rb = erel[k + 4] - r0;
        float e0 = esc[k], e1 = esc[k + 4];
        float4 v0 = *(const float4*)(y + ((size_t)ra * NN + s0) * 64 + q * 4);
        float4 v1 = *(const float4*)(y + ((size_t)rb * NN + s1) * 64 + q * 4);
        fmacc(acc, v0, e0);
        fmacc(acc, v1, e1);
    }
    if (k < end) {
        int s0 = srcs[k];
        int ra = erel[k] - r0;
        float4 v0 = *(const float4*)(y + ((size_t)ra * NN + s0) * 64 + q * 4);
        fmacc(acc, v0, esc[k]);
    }
    red4(acc, 16);
    red4(acc, 32);
    if (lane < 16) {
        float4 prev = *(const float4*)(x1 + (size_t)n * 64 + q * 4);
        float4 v = make_float4(prev.x + acc.x, prev.y + acc.y, prev.z + acc.z, prev.w + acc.w);
        if (final_pass) {
            float4 b = *(const float4*)(bias + q * 4);
            v.x = fmaxf(v.x + b.x, 0.f);
            v.y = fmaxf(v.y + b.y, 0.f);
            v.z = fmaxf(v.z + b.z, 0.f);
            v.w = fmaxf(v.w + b.w, 0.f);
        }
        *(float4*)(x1 + (size_t)n * 64 + q * 4) = v;
    }
}

// ===== aggregate 2: 8 edge-groups x 8 lanes; single pass, 8 rel; x3 pre-holds x2@root2 =====
__global__ __launch_bounds__(256) void k_agg2(const int* __restrict__ rp,
                                              const int* __restrict__ srcs,
                                              const unsigned char* __restrict__ erel,
                                              const float* __restrict__ esc,
                                              const float* __restrict__ y,
                                              const float* __restrict__ bias,
                                              float* __restrict__ x3) {
    int wid = threadIdx.x >> 6, lane = threadIdx.x & 63;
    int n = blockIdx.x * 4 + wid;
    int q = lane & 7;
    int beg = rp[n * RR], end = rp[n * RR + RR];
    float4 acc = make_float4(0.f, 0.f, 0.f, 0.f);
    int k = beg + (lane >> 3);
    for (; k + 8 < end; k += 16) {
        int s0 = srcs[k], s1 = srcs[k + 8];
        int g0 = erel[k], g1 = erel[k + 8];
        float e0 = esc[k], e1 = esc[k + 8];
        float4 v0 = *(const float4*)(y + ((size_t)(g0 >> 1) * NN + s0) * 64 + (g0 & 1) * 32 + q * 4);
        float4 v1 = *(const float4*)(y + ((size_t)(g1 >> 1) * NN + s1) * 64 + (g1 & 1) * 32 + q * 4);
        fmacc(acc, v0, e0);
        fmacc(acc, v1, e1);
    }
    if (k < end) {
        int s0 = srcs[k];
        int g0 = erel[k];
        float4 v0 = *(const float4*)(y + ((size_t)(g0 >> 1) * NN + s0) * 64 + (g0 & 1) * 32 + q * 4);
        fmacc(acc, v0, esc[k]);
    }
    red4(acc, 8);
    red4(acc, 16);
    red4(acc, 32);
    if (lane < 8) {
        float4 prev = *(const float4*)(x3 + (size_t)n * 32 + q * 4);
        float4 b = *(const float4*)(bias + q * 4);
        float4 v;
        v.x = fmaxf(prev.x + acc.x + b.x, 0.f);
        v.y = fmaxf(prev.y + acc.y + b.y, 0.f);
        v.z = fmaxf(prev.z + acc.z + b.z, 0.f);
        v.w = fmaxf(prev.w + acc.w + b.w, 0.f);
        *(float4*)(x3 + (size_t)n * 32 + q * 4) = v;
    }
}

// ===== attention logits from x: als[n,h] = x[n]·U[:,h], ald[n,h] = x[n]·U[:,4+h] =====
template <int F>
__global__ void k_al(const float* __restrict__ X, const float* __restrict__ U,
                     float* __restrict__ als, float* __restrict__ ald) {
    int i = blockIdx.x * 256 + threadIdx.x;  // i = n*8 + j
    if (i >= NN * 8) return;
    int n = i >> 3, j = i & 7;
    const float* xp = X + (size_t)n * F;
    float s = 0.f;
    for (int c = 0; c < F; c++) s += xp[c] * U[c * 8 + j];
    if (j < 4) als[n * 4 + j] = s;
    else ald[n * 4 + (j - 4)] = s;
}

// ===== fused GAT aggregation in INPUT space: msg[n][h][F] = (Σ_e p_e,h x[s_e]) / z_h =====
// F/4 lanes per edge-group; 4 head-accumulators per lane; self-loop in group 0.
template <int F>
__global__ __launch_bounds__(256) void k_gatx(const int* __restrict__ rp,
                                              const int* __restrict__ srcs,
                                              const float* __restrict__ als,
                                              const float* __restrict__ ald,
                                              const float* __restrict__ X,
                                              float* __restrict__ msg) {
    constexpr int G = F / 4;    // lanes per edge-group (16 or 8)
    constexpr int NG = 64 / G;  // groups per wave (4 or 8)
    int wid = threadIdx.x >> 6, lane = threadIdx.x & 63;
    int n = blockIdx.x * 4 + wid;
    if (n >= NN) return;
    int g = lane / G, q = lane % G;
    float4 ald4 = *(const float4*)(ald + n * 4);
    float4 acc0 = make_float4(0.f, 0.f, 0.f, 0.f);
    float4 acc1 = acc0, acc2 = acc0, acc3 = acc0;
    float4 z = make_float4(0.f, 0.f, 0.f, 0.f);
    if (g == 0) {  // self loop
        float4 a4 = *(const float4*)(als + n * 4);
        float4 xv = *(const float4*)(X + (size_t)n * F + q * 4);
        float p0 = __expf(leaky(a4.x + ald4.x));
        float p1 = __expf(leaky(a4.y + ald4.y));
        float p2 = __expf(leaky(a4.z + ald4.z));
        float p3 = __expf(leaky(a4.w + ald4.w));
        z = make_float4(p0, p1, p2, p3);
        fmacc(acc0, xv, p0);
        fmacc(acc1, xv, p1);
        fmacc(acc2, xv, p2);
        fmacc(acc3, xv, p3);
    }
    int beg = rp[n * RR], end = rp[n * RR + RR];
    int k = beg + g;
    for (; k + NG < end; k += 2 * NG) {
        int s0 = srcs[k], s1 = srcs[k + NG];
        float4 a0 = *(const float4*)(als + s0 * 4);
        float4 a1 = *(const float4*)(als + s1 * 4);
        float4 x0 = *(const float4*)(X + (size_t)s0 * F + q * 4);
        float4 x1v = *(const float4*)(X + (size_t)s1 * F + q * 4);
        float p00 = __expf(leaky(a0.x + ald4.x)), p01 = __expf(leaky(a0.y + ald4.y));
        float p02 = __expf(leaky(a0.z + ald4.z)), p03 = __expf(leaky(a0.w + ald4.w));
        float p10 = __expf(leaky(a1.x + ald4.x)), p11 = __expf(leaky(a1.y + ald4.y));
        float p12 = __expf(leaky(a1.z + ald4.z)), p13 = __expf(leaky(a1.w + ald4.w));
        z.x += p00 + p10;
        z.y += p01 + p11;
        z.z += p02 + p12;
        z.w += p03 + p13;
        fmacc(acc0, x0, p00);
        fmacc(acc1, x0, p01);
        fmacc(acc2, x0, p02);
        fmacc(acc3, x0, p03);
        fmacc(acc0, x1v, p10);
        fmacc(acc1, x1v, p11);
        fmacc(acc2, x1v, p12);
        fmacc(acc3, x1v, p13);
    }
    if (k < end) {
        int s0 = srcs[k];
        float4 a0 = *(const float4*)(als + s0 * 4);
        float4 x0 = *(const float4*)(X + (size_t)s0 * F + q * 4);
        float p00 = __expf(leaky(a0.x + ald4.x)), p01 = __expf(leaky(a0.y + ald4.y));
        float p02 = __expf(leaky(a0.z + ald4.z)), p03 = __expf(leaky(a0.w + ald4.w));
        z.x += p00;
        z.y += p01;
        z.z += p02;
        z.w += p03;
        fmacc(acc0, x0, p00);
        fmacc(acc1, x0, p01);
        fmacc(acc2, x0, p02);
        fmacc(acc3, x0, p03);
    }
#pragma unroll
    for (int m = G; m < 64; m <<= 1) {
        red4(acc0, m);
        red4(acc1, m);
        red4(acc2, m);
        red4(acc3, m);
        red4(z, m);
    }
    if (g == 0) {
        float4 iz = make_float4(1.f / z.x, 1.f / z.y, 1.f / z.z, 1.f / z.w);
        float* mp = msg + (size_t)n * 4 * F + q * 4;
        *(float4*)(mp + 0 * F) = make_float4(acc0.x * iz.x, acc0.y * iz.x, acc0.z * iz.x, acc0.w * iz.x);
        *(float4*)(mp + 1 * F) = make_float4(acc1.x * iz.y, acc1.y * iz.y, acc1.z * iz.y, acc1.w * iz.y);
        *(float4*)(mp + 2 * F) = make_float4(acc2.x * iz.z, acc2.y * iz.z, acc2.z * iz.z, acc2.w * iz.z);
        *(float4*)(mp + 3 * F) = make_float4(acc3.x * iz.w, acc3.y * iz.w, acc3.z * iz.w, acc3.w * iz.w);
    }
}

// ===== final: out = tanh(relu(S/4 + bias)) =====
__global__ void k_final(const float* __restrict__ S, const float* __restrict__ bias,
                        float* __restrict__ out) {
    int i = blockIdx.x * 256 + threadIdx.x;
    if (i >= NN * 16) return;
    int c = i & 15;
    float v = fmaxf(0.25f * S[i] + bias[c], 0.f);
    out[i] = tanhf(v);
}

extern "C" void kernel_launch(void* const* d_in, const int* in_sizes, int n_in,
                              void* d_out, int out_size, void* d_ws, size_t ws_size,
                              hipStream_t stream) {
    const float* x      = (const float*)d_in[0];
    const int*   ei     = (const int*)d_in[1];
    const int*   et     = (const int*)d_in[2];
    const float* basis1 = (const float*)d_in[3];
    const float* comp1  = (const float*)d_in[4];
    const float* root1  = (const float*)d_in[5];
    const float* brg1   = (const float*)d_in[6];
    const float* wg1    = (const float*)d_in[7];
    const float* asrc1  = (const float*)d_in[8];
    const float* adst1  = (const float*)d_in[9];
    const float* bg1    = (const float*)d_in[10];
    const float* basis2 = (const float*)d_in[11];
    const float* comp2  = (const float*)d_in[12];
    const float* root2  = (const float*)d_in[13];
    const float* brg2   = (const float*)d_in[14];
    const float* wg2    = (const float*)d_in[15];
    const float* asrc2  = (const float*)d_in[16];
    const float* adst2  = (const float*)d_in[17];
    const float* bg2    = (const float*)d_in[18];
    const int* src = ei;
    const int* dst = ei + EE;
    float* out = (float*)d_out;

    // ---- int region ----
    int* wsi = (int*)d_ws;
    size_t ioff = 0;
    auto ialloc = [&](size_t n) { int* p = wsi + ioff; ioff += (n + 3) & ~(size_t)3; return p; };
    int* cnt2 = ialloc(SEGS);  // reused as fill cursors (wo)
    int* rp   = ialloc(SEGS + 1);
    int* bsum = ialloc(2048);
    int* srcs = ialloc(EE);
    unsigned char* erel = (unsigned char*)ialloc((EE + 3) / 4);
    int* wo = cnt2;
    // ---- float region ----
    float* wsf = (float*)(wsi + ioff);
    size_t total_f = (ws_size - ioff * sizeof(int)) / sizeof(float);
    size_t ybuf_f = (size_t)4 * NN * 64;  // = NN*256 (msg1) = 8*NN*32 (L3 y) >= NN*128 (msg2)
    size_t need_f = (size_t)EE + ybuf_f + (size_t)NN * 64 + (size_t)NN * 128
                  + 2 * (size_t)RR * 4096 + 16384 + 8192 + 8192 + 512 + 256
                  + 2 * (size_t)NN * 4 + 64;
    if (total_f < need_f) return;  // loud fail: output stays zero
    size_t foff = 0;
    auto falloc = [&](size_t n) { float* p = wsf + foff; foff += (n + 3) & ~(size_t)3; return p; };
    float* esc   = falloc(EE);
    float* ybuf  = falloc(ybuf_f);           // y (L1), msg1, y (L3), msg2
    float* x1    = falloc((size_t)NN * 64);  // layer-1 out; later x3 (first NN*32)
    float* x2    = falloc((size_t)NN * 128); // layer-2 out; later S scratch
    float* Wcat1 = falloc((size_t)RR * 4096);
    float* Wcat2 = falloc((size_t)RR * 4096);
    float* wg1r  = falloc(16384);
    float* Wstk  = falloc(8192);
    float* Wr2p  = falloc(8192);
    float* U1    = falloc(512);
    float* U2    = falloc(256);
    float* als   = falloc((size_t)NN * 4);
    float* ald   = falloc((size_t)NN * 4);
    float* msg1 = ybuf;  // [n][4][64]
    float* msg2 = ybuf;  // [n][4][32]
    float* x3 = x1;      // x1 dead after k_gatx<64>
    float* S  = x2;      // x2 dead after L3 y-gemm

    const int EB = (EE + 255) / 256;
    const int NB4 = (NN + 3) / 4;   // NN % 4 == 0 -> exact, no early-exit divergence
    const int NT = (NN + 63) / 64;

    // ---- CSR build ----
    hipMemsetAsync(cnt2, 0, SEGS * sizeof(int), stream);
    k_count2<<<EB, 256, 0, stream>>>(dst, et, cnt2);
    k_scanA<<<NBLK, 256, 0, stream>>>(cnt2, rp, bsum);
    k_scanB<<<1, 256, 0, stream>>>(bsum);
    k_scanC<<<NBLK, 256, 0, stream>>>(rp, bsum, wo);
    k_fill<<<EB, 256, 0, stream>>>(src, dst, et, rp, wo, srcs, erel, esc);
    k_weights<<<(2 * RR * 4096) / 256, 256, 0, stream>>>(basis1, comp1, basis2, comp2, Wcat1, Wcat2);
    k_prep<<<(16384 + 8192 + 8192 + 512 + 256 + 255) / 256, 256, 0, stream>>>(
        wg1, wg2, root2, asrc1, adst1, asrc2, adst2, wg1r, Wstk, Wr2p, U1, U2);

    // ---- layer 1: RGCN(64->64)+relu; x1 pre-init with x@root1, then 2 gather passes ----
    k_gemm64<64><<<dim3(NT, 1), 256, 0, stream>>>(x, 64, 0, root1, 64, 0, x1, 64, 0, nullptr, 0);
    for (int r0 = 0; r0 < RR; r0 += 4) {
        k_gemm64<64><<<dim3(NT, 4), 256, 0, stream>>>(x, 64, 0, Wcat1 + r0 * 64, 512, 64,
                                                      ybuf, 64, (size_t)NN * 64, nullptr, 0);
        k_agg1<<<NB4, 256, 0, stream>>>(rp, srcs, erel, esc, ybuf, brg1, x1, r0, 4, r0 == 4);
    }

    // ---- layer 2: GAT(64 -> 4x32 concat), aggregated in input space ----
    k_al<64><<<(NN * 8 + 255) / 256, 256, 0, stream>>>(x1, U1, als, ald);
    k_gatx<64><<<NB4, 256, 0, stream>>>(rp, srcs, als, ald, x1, msg1);
    k_gemm64<64, 32><<<dim3(NT, 4), 256, 0, stream>>>(msg1, 256, 64, wg1r, 64, 4096,
                                                      x2, 128, 32, bg1, 32);

    // ---- layer 3: RGCN(128->32)+relu; x3 pre-init with x2@root2, single gather pass ----
    k_gemm64<128, 32><<<dim3(NT, 1), 256, 0, stream>>>(x2, 128, 0, Wr2p, 64, 0,
                                                       x3, 32, 0, nullptr, 0);
    k_gemm64<128><<<dim3(NT, 4), 256, 0, stream>>>(x2, 128, 0, Wcat2, 256, 64,
                                                   ybuf, 64, (size_t)NN * 64, nullptr, 0);
    k_agg2<<<NB4, 256, 0, stream>>>(rp, srcs, erel, esc, ybuf, brg2, x3);

    // ---- layer 4: GAT(32 -> 4x16, mean heads) + relu + tanh ----
    k_al<32><<<(NN * 8 + 255) / 256, 256, 0, stream>>>(x3, U2, als, ald);
    k_gatx<32><<<NB4, 256, 0, stream>>>(rp, srcs, als, ald, x3, msg2);
    k_gemm64<128, 16><<<dim3(NT, 1), 256, 0, stream>>>(msg2, 128, 0, Wstk, 64, 0,
                                                       S, 16, 0, nullptr, 0);
    k_final<<<(NN * 16 + 255) / 256, 256, 0, stream>>>(S, bg2, out);
}